// Round 1
// baseline (933.519 us; speedup 1.0000x reference)
//
#include <hip/hip_runtime.h>
#include <hip/hip_bf16.h>
#include <math.h>

typedef __bf16 bf16x8 __attribute__((ext_vector_type(8)));
typedef float  f32x4  __attribute__((ext_vector_type(4)));

#define HDIM   512
#define FLAT   65792
#define DIN    66304
#define G3     1536          // 3*H
#define NSLAB  2056          // FLAT / 32
#define NPAD   544           // padded GEMM N: 512 (M) + 1 (b_proj) + 1 (start) + 30 zero
#define LPITCH 40            // LDS row pitch in ushorts (80 B -> 2-way-free banks)
#define MT     128           // GEMM M tile
#define KSPLIT 21
#define CHUNK  98            // slabs per K chunk (21*98 >= 2056)

// Bh bytes = NSLAB * NPAD * 32 ... = 2056 * 17408 ushorts = 71,581,696 B
// (round-1 bug: this was understated by 8 KB -> Bh tail aliased Mbuf head ->
//  fp32 atomic partials re-read as bf16 B-fragments -> NaN. Offsets now exact.)
#define BH_BYTES  71581696ULL
#define MBUF_BYTES 3342336ULL   // G3*NPAD*4
#define GIB_BYTES   393216ULL   // 64*G3*4
#define HALL_BYTES  131072ULL   // 64*512*4
#define HBF_BYTES    65536ULL   // 64*512*2

__device__ __forceinline__ ushort f2bf(float f) {
    uint u = __float_as_uint(f);
    u += 0x7FFFu + ((u >> 16) & 1u);   // round-to-nearest-even
    return (ushort)(u >> 16);
}

// ---------------------------------------------------------------------------
// K1 (fast path): build blocked bf16 B matrix for the big GEMM.
// Bh[slab][n][kk] = B[k = slab*32+kk][n], n<512: W_proj[k][n], 512: b_proj[k],
// 513: start_token[k], 514..543: 0.
// ---------------------------------------------------------------------------
__global__ __launch_bounds__(256) void buildBh(const float* __restrict__ Wp,
                                               const float* __restrict__ bproj,
                                               const float* __restrict__ start,
                                               ushort* __restrict__ Bh) {
    __shared__ ushort tr[512 * 33];   // [n][k] pitch 33 (67,584 B static LDS: ok on gfx950)
    const int slab = blockIdx.x;
    const int tid  = threadIdx.x;
    for (int idx = tid; idx < 32 * 512; idx += 256) {
        const int k = idx >> 9;
        const int n = idx & 511;
        tr[n * 33 + k] = f2bf(Wp[(size_t)(slab * 32 + k) * 512 + n]);
    }
    __syncthreads();
    uint* out = (uint*)(Bh + (size_t)slab * 17408);
    for (int d = tid; d < 8704; d += 256) {
        const int n  = d >> 4;
        const int k2 = (d & 15) * 2;
        ushort lo, hi;
        if (n < 512)      { lo = tr[n * 33 + k2];            hi = tr[n * 33 + k2 + 1]; }
        else if (n == 512){ lo = f2bf(bproj[slab * 32 + k2]); hi = f2bf(bproj[slab * 32 + k2 + 1]); }
        else if (n == 513){ lo = f2bf(start[slab * 32 + k2]); hi = f2bf(start[slab * 32 + k2 + 1]); }
        else              { lo = 0; hi = 0; }
        out[d] = (uint)lo | ((uint)hi << 16);
    }
}

// ---------------------------------------------------------------------------
// K2 (fast path): M = W_ih[:,512:] @ [W_proj | b_proj | start | 0pad] (1536x544)
// split-K, bf16 MFMA 16x16x32, fp32 atomicAdd accumulation into Mbuf.
// Block: 1024 thr (16 waves, 8Mx2N), C-tile 128x544, single-buffer LDS,
// register prefetch of next k-slab under MFMA.
// ---------------------------------------------------------------------------
__global__ __launch_bounds__(1024) void gemmM(const float* __restrict__ Wih,
                                              const ushort* __restrict__ Bh,
                                              float* __restrict__ Mbuf) {
    __shared__ ushort Alds[MT * LPITCH];     // 10240 B
    __shared__ ushort Blds[NPAD * LPITCH];   // 43520 B
    const int tid  = threadIdx.x;
    const int lane = tid & 63;
    const int wave = tid >> 6;
    const int wm   = wave >> 1;       // 0..7  -> rows wm*16
    const int wn   = wave & 1;        // 0..1  -> cols wn*272
    const int lrow = lane & 15;
    const int quad = lane >> 4;
    const int bid   = blockIdx.x;
    const int mtile = bid % 12;
    const int kc    = bid / 12;
    const int s0 = kc * CHUNK;
    const int s1 = min(s0 + CHUNK, NSLAB);

    const int arow = tid >> 3;
    const int aseg = tid & 7;
    const float* aPtr = Wih + (size_t)(mtile * MT + arow) * DIN + 512 + aseg * 4;

    f32x4 acc[17];
#pragma unroll
    for (int t = 0; t < 17; ++t) acc[t] = (f32x4){0.f, 0.f, 0.f, 0.f};

    float4 aReg;
    uint4  bReg0 = {}, bReg1 = {}, bReg2 = {};
    {
        const size_t sb = (size_t)s0 * 17408;
        aReg  = *(const float4*)(aPtr + (size_t)s0 * 32);
        bReg0 = *(const uint4*)(Bh + sb + (size_t)tid * 8);
        bReg1 = *(const uint4*)(Bh + sb + (size_t)(tid + 1024) * 8);
        if (tid < 128) bReg2 = *(const uint4*)(Bh + sb + (size_t)(tid + 2048) * 8);
    }
    for (int s = s0; s < s1; ++s) {
        {
            uint2 ap;
            ap.x = (uint)f2bf(aReg.x) | ((uint)f2bf(aReg.y) << 16);
            ap.y = (uint)f2bf(aReg.z) | ((uint)f2bf(aReg.w) << 16);
            *(uint2*)&Alds[arow * LPITCH + aseg * 4] = ap;
            *(uint4*)&Blds[(tid >> 2) * LPITCH + (tid & 3) * 8] = bReg0;
            const int c1 = tid + 1024;
            *(uint4*)&Blds[(c1 >> 2) * LPITCH + (c1 & 3) * 8] = bReg1;
            if (tid < 128) {
                const int c2 = tid + 2048;
                *(uint4*)&Blds[(c2 >> 2) * LPITCH + (c2 & 3) * 8] = bReg2;
            }
        }
        __syncthreads();
        if (s + 1 < s1) {
            const size_t sb = (size_t)(s + 1) * 17408;
            aReg  = *(const float4*)(aPtr + (size_t)(s + 1) * 32);
            bReg0 = *(const uint4*)(Bh + sb + (size_t)tid * 8);
            bReg1 = *(const uint4*)(Bh + sb + (size_t)(tid + 1024) * 8);
            if (tid < 128) bReg2 = *(const uint4*)(Bh + sb + (size_t)(tid + 2048) * 8);
        }
        const bf16x8 af = __builtin_bit_cast(bf16x8,
            *(const uint4*)&Alds[(wm * 16 + lrow) * LPITCH + quad * 8]);
#pragma unroll
        for (int t = 0; t < 17; ++t) {
            const bf16x8 bf = __builtin_bit_cast(bf16x8,
                *(const uint4*)&Blds[(wn * 272 + t * 16 + lrow) * LPITCH + quad * 8]);
            acc[t] = __builtin_amdgcn_mfma_f32_16x16x32_bf16(af, bf, acc[t], 0, 0, 0);
        }
        __syncthreads();
    }
#pragma unroll
    for (int t = 0; t < 17; ++t) {
        const int col = wn * 272 + t * 16 + lrow;
#pragma unroll
        for (int r = 0; r < 4; ++r) {
            const int row = mtile * MT + wm * 16 + quad * 4 + r;
            atomicAdd(&Mbuf[(size_t)row * NPAD + col], acc[t][r]);
        }
    }
}

// ---------------------------------------------------------------------------
// K2' (fallback, small ws_size): same GEMM but reads W_proj fp32 directly and
// transposes in-LDS per slab (scalar ds_write_u16 stores). ~3.9 MB workspace.
// ---------------------------------------------------------------------------
__global__ __launch_bounds__(1024) void gemmMDirect(const float* __restrict__ Wih,
                                                    const float* __restrict__ Wp,
                                                    const float* __restrict__ bproj,
                                                    const float* __restrict__ start,
                                                    float* __restrict__ Mbuf) {
    __shared__ ushort Alds[MT * LPITCH];
    __shared__ ushort Blds[NPAD * LPITCH];
    const int tid  = threadIdx.x;
    const int lane = tid & 63;
    const int wave = tid >> 6;
    const int wm   = wave >> 1;
    const int wn   = wave & 1;
    const int lrow = lane & 15;
    const int quad = lane >> 4;
    const int bid   = blockIdx.x;
    const int mtile = bid % 12;
    const int kc    = bid / 12;
    const int s0 = kc * CHUNK;
    const int s1 = min(s0 + CHUNK, NSLAB);

    const int arow = tid >> 3;
    const int aseg = tid & 7;
    const float* aPtr = Wih + (size_t)(mtile * MT + arow) * DIN + 512 + aseg * 4;

    // B staging map: k = tid>>5 (0..31), n = (tid&31)*4 + q*128 + i
    const int bk = tid >> 5;
    const int bn0 = (tid & 31) * 4;
    // extra cols: tid<64 -> which = tid>>5 (0:bproj,1:start), k = tid&31
    const int ek = tid & 31;
    const float* esrc = (tid < 32) ? bproj : start;

    // zero pad rows 514..543 once (never overwritten afterwards)
    for (int idx = tid; idx < 30 * LPITCH; idx += 1024) Blds[514 * LPITCH + idx] = 0;

    f32x4 acc[17];
#pragma unroll
    for (int t = 0; t < 17; ++t) acc[t] = (f32x4){0.f, 0.f, 0.f, 0.f};

    float4 aReg;
    float4 bReg[4];
    float  eReg = 0.f;
    {
        aReg = *(const float4*)(aPtr + (size_t)s0 * 32);
        const float* bbase = Wp + (size_t)(s0 * 32 + bk) * 512 + bn0;
#pragma unroll
        for (int q = 0; q < 4; ++q) bReg[q] = *(const float4*)(bbase + q * 128);
        if (tid < 64) eReg = esrc[s0 * 32 + ek];
    }
    for (int s = s0; s < s1; ++s) {
        {
            uint2 ap;
            ap.x = (uint)f2bf(aReg.x) | ((uint)f2bf(aReg.y) << 16);
            ap.y = (uint)f2bf(aReg.z) | ((uint)f2bf(aReg.w) << 16);
            *(uint2*)&Alds[arow * LPITCH + aseg * 4] = ap;
#pragma unroll
            for (int q = 0; q < 4; ++q) {
                const int n = bn0 + q * 128;
                Blds[(n + 0) * LPITCH + bk] = f2bf(bReg[q].x);
                Blds[(n + 1) * LPITCH + bk] = f2bf(bReg[q].y);
                Blds[(n + 2) * LPITCH + bk] = f2bf(bReg[q].z);
                Blds[(n + 3) * LPITCH + bk] = f2bf(bReg[q].w);
            }
            if (tid < 64) Blds[(512 + (tid >> 5)) * LPITCH + ek] = f2bf(eReg);
        }
        __syncthreads();
        if (s + 1 < s1) {
            aReg = *(const float4*)(aPtr + (size_t)(s + 1) * 32);
            const float* bbase = Wp + (size_t)((s + 1) * 32 + bk) * 512 + bn0;
#pragma unroll
            for (int q = 0; q < 4; ++q) bReg[q] = *(const float4*)(bbase + q * 128);
            if (tid < 64) eReg = esrc[(s + 1) * 32 + ek];
        }
        const bf16x8 af = __builtin_bit_cast(bf16x8,
            *(const uint4*)&Alds[(wm * 16 + lrow) * LPITCH + quad * 8]);
#pragma unroll
        for (int t = 0; t < 17; ++t) {
            const bf16x8 bf = __builtin_bit_cast(bf16x8,
                *(const uint4*)&Blds[(wn * 272 + t * 16 + lrow) * LPITCH + quad * 8]);
            acc[t] = __builtin_amdgcn_mfma_f32_16x16x32_bf16(af, bf, acc[t], 0, 0, 0);
        }
        __syncthreads();
    }
#pragma unroll
    for (int t = 0; t < 17; ++t) {
        const int col = wn * 272 + t * 16 + lrow;
#pragma unroll
        for (int r = 0; r < 4; ++r) {
            const int row = mtile * MT + wm * 16 + quad * 4 + r;
            atomicAdd(&Mbuf[(size_t)row * NPAD + col], acc[t][r]);
        }
    }
}

// ---------------------------------------------------------------------------
// K3: gi_base[pair][j] = b_ih[j] + W_ih[j,:256]@content[b,s] + W_ih[j,256:512]@style[b]
//                        + (s==0 ? (A@start)[j] : (A@b_proj)[j])
// ---------------------------------------------------------------------------
__global__ __launch_bounds__(256) void giBase(const float* __restrict__ Wih,
                                              const float* __restrict__ content,
                                              const float* __restrict__ style,
                                              const float* __restrict__ bih,
                                              const float* __restrict__ Mbuf,
                                              float* __restrict__ giB) {
    const int j = (blockIdx.x * blockDim.x + threadIdx.x) >> 6;
    if (j >= G3) return;
    const int lane = threadIdx.x & 63;   // pair = b*16 + s
    const int b = lane >> 4;
    const int s = lane & 15;
    const float* wr = Wih + (size_t)j * DIN;
    const float* cp = content + (size_t)lane * 256;
    const float* sp = style + (size_t)b * 256;
    float acc = 0.f;
#pragma unroll 4
    for (int d = 0; d < 256; d += 4) {
        const float4 w = *(const float4*)(wr + d);
        const float4 x = *(const float4*)(cp + d);
        acc += w.x * x.x + w.y * x.y + w.z * x.z + w.w * x.w;
    }
#pragma unroll 4
    for (int d = 0; d < 256; d += 4) {
        const float4 w = *(const float4*)(wr + 256 + d);
        const float4 x = *(const float4*)(sp + d);
        acc += w.x * x.x + w.y * x.y + w.z * x.z + w.w * x.w;
    }
    acc += bih[j] + ((s == 0) ? Mbuf[(size_t)j * NPAD + 513] : Mbuf[(size_t)j * NPAD + 512]);
    giB[(size_t)lane * G3 + j] = acc;
}

// ---------------------------------------------------------------------------
// K4 (x16): one GRU step. Wave per (b, j): six 512-length dots, shuffle-reduce.
// ---------------------------------------------------------------------------
__global__ __launch_bounds__(256) void stepK(const float* __restrict__ Mbuf,
                                             const float* __restrict__ Whh,
                                             const float* __restrict__ bhh,
                                             const float* __restrict__ giB,
                                             float* __restrict__ hAll,
                                             ushort* __restrict__ hBf,
                                             const int s) {
    const int gw   = (blockIdx.x * blockDim.x + threadIdx.x) >> 6;  // 0..2047
    const int lane = threadIdx.x & 63;
    const int b = gw & 3;
    const int j = gw >> 2;          // 0..511
    float dMr = 0.f, dMz = 0.f, dMn = 0.f, dWr = 0.f, dWz = 0.f, dWn = 0.f;
    if (s > 0) {
        const float* h = hAll + (size_t)((s - 1) * 4 + b) * HDIM;
        float hr[8];
#pragma unroll
        for (int i = 0; i < 8; ++i) hr[i] = h[i * 64 + lane];
        const float* M0 = Mbuf + (size_t)j * NPAD;
        const float* M1 = Mbuf + (size_t)(j + 512) * NPAD;
        const float* M2 = Mbuf + (size_t)(j + 1024) * NPAD;
        const float* W0 = Whh + (size_t)j * HDIM;
        const float* W1 = Whh + (size_t)(j + 512) * HDIM;
        const float* W2 = Whh + (size_t)(j + 1024) * HDIM;
#pragma unroll
        for (int i = 0; i < 8; ++i) {
            const int d = i * 64 + lane;
            dMr += M0[d] * hr[i]; dMz += M1[d] * hr[i]; dMn += M2[d] * hr[i];
            dWr += W0[d] * hr[i]; dWz += W1[d] * hr[i]; dWn += W2[d] * hr[i];
        }
#pragma unroll
        for (int m = 1; m < 64; m <<= 1) {
            dMr += __shfl_xor(dMr, m); dMz += __shfl_xor(dMz, m); dMn += __shfl_xor(dMn, m);
            dWr += __shfl_xor(dWr, m); dWz += __shfl_xor(dWz, m); dWn += __shfl_xor(dWn, m);
        }
    }
    if (lane == 0) {
        const float* gb = giB + (size_t)(b * 16 + s) * G3;
        const float gir = gb[j] + dMr;
        const float giz = gb[j + 512] + dMz;
        const float gin = gb[j + 1024] + dMn;
        const float ghr = bhh[j] + dWr;
        const float ghz = bhh[j + 512] + dWz;
        const float ghn = bhh[j + 1024] + dWn;
        const float r = 1.f / (1.f + expf(-(gir + ghr)));
        const float z = 1.f / (1.f + expf(-(giz + ghz)));
        const float n = tanhf(gin + r * ghn);
        const float hp = (s > 0) ? hAll[(size_t)((s - 1) * 4 + b) * HDIM + j] : 0.f;
        const float hn = (1.f - z) * n + z * hp;
        hAll[(size_t)(s * 4 + b) * HDIM + j] = hn;
        hBf[(size_t)(s * 4 + b) * HDIM + j] = f2bf(hn);
    }
}

// ---------------------------------------------------------------------------
// K5: out[b][s][f] = W_proj[f] . h[s*4+b] + b_proj[f], MFMA bf16.
// ---------------------------------------------------------------------------
__global__ __launch_bounds__(256) void projK(const float* __restrict__ Wp,
                                             const float* __restrict__ bproj,
                                             const ushort* __restrict__ hBf,
                                             float* __restrict__ out) {
    const int lane = threadIdx.x & 63;
    const int wave = threadIdx.x >> 6;
    const int f0   = blockIdx.x * 256 + wave * 64;
    const int lrow = lane & 15;
    const int quad = lane >> 4;
    f32x4 acc[4][4];
#pragma unroll
    for (int pt = 0; pt < 4; ++pt)
#pragma unroll
        for (int ft = 0; ft < 4; ++ft) acc[pt][ft] = (f32x4){0.f, 0.f, 0.f, 0.f};

    for (int d0 = 0; d0 < HDIM; d0 += 32) {
        bf16x8 afr[4];
#pragma unroll
        for (int pt = 0; pt < 4; ++pt)
            afr[pt] = __builtin_bit_cast(bf16x8,
                *(const uint4*)(hBf + (size_t)(pt * 16 + lrow) * HDIM + d0 + quad * 8));
#pragma unroll
        for (int ft = 0; ft < 4; ++ft) {
            const float* wrow = Wp + (size_t)(f0 + ft * 16 + lrow) * HDIM + d0 + quad * 8;
            const float4 w0 = *(const float4*)(wrow);
            const float4 w1 = *(const float4*)(wrow + 4);
            uint4 pr;
            pr.x = (uint)f2bf(w0.x) | ((uint)f2bf(w0.y) << 16);
            pr.y = (uint)f2bf(w0.z) | ((uint)f2bf(w0.w) << 16);
            pr.z = (uint)f2bf(w1.x) | ((uint)f2bf(w1.y) << 16);
            pr.w = (uint)f2bf(w1.z) | ((uint)f2bf(w1.w) << 16);
            const bf16x8 bfr = __builtin_bit_cast(bf16x8, pr);
#pragma unroll
            for (int pt = 0; pt < 4; ++pt)
                acc[pt][ft] = __builtin_amdgcn_mfma_f32_16x16x32_bf16(afr[pt], bfr, acc[pt][ft], 0, 0, 0);
        }
    }
#pragma unroll
    for (int pt = 0; pt < 4; ++pt)
#pragma unroll
        for (int ft = 0; ft < 4; ++ft) {
            const int f = f0 + ft * 16 + lrow;
            const float bp = bproj[f];
#pragma unroll
            for (int r = 0; r < 4; ++r) {
                const int p = pt * 16 + quad * 4 + r;   // pair index = s*4 + b
                const int ss = p >> 2;
                const int bb = p & 3;
                out[(size_t)(bb * 16 + ss) * FLAT + f] = acc[pt][ft][r] + bp;
            }
        }
}

// ---------------------------------------------------------------------------
extern "C" void kernel_launch(void* const* d_in, const int* in_sizes, int n_in,
                              void* d_out, int out_size, void* d_ws, size_t ws_size,
                              hipStream_t stream) {
    const float* content = (const float*)d_in[0];  // (4,16,256)
    const float* style   = (const float*)d_in[1];  // (4,256)
    const float* start   = (const float*)d_in[2];  // (65792)
    const float* Wih     = (const float*)d_in[3];  // (1536, 66304)
    const float* Whh     = (const float*)d_in[4];  // (1536, 512)
    const float* bih     = (const float*)d_in[5];  // (1536)
    const float* bhh     = (const float*)d_in[6];  // (1536)
    const float* Wproj   = (const float*)d_in[7];  // (65792, 512)
    const float* bproj   = (const float*)d_in[8];  // (65792)
    float* out = (float*)d_out;

    const size_t needFast = BH_BYTES + MBUF_BYTES + GIB_BYTES + HALL_BYTES + HBF_BYTES;
    const bool fast = (ws_size >= needFast);   // constant per deployment -> graph-safe

    char* ws = (char*)d_ws;
    const size_t base = fast ? BH_BYTES : 0;
    ushort* Bh   = (ushort*)ws;
    float*  Mbuf = (float*)(ws + base);
    float*  giB  = (float*)(ws + base + MBUF_BYTES);
    float*  hAll = (float*)(ws + base + MBUF_BYTES + GIB_BYTES);
    ushort* hBf  = (ushort*)(ws + base + MBUF_BYTES + GIB_BYTES + HALL_BYTES);

    hipMemsetAsync(Mbuf, 0, MBUF_BYTES, stream);
    if (fast) {
        buildBh<<<NSLAB, 256, 0, stream>>>(Wproj, bproj, start, Bh);
        gemmM<<<12 * KSPLIT, 1024, 0, stream>>>(Wih, Bh, Mbuf);
    } else {
        gemmMDirect<<<12 * KSPLIT, 1024, 0, stream>>>(Wih, Wproj, bproj, start, Mbuf);
    }
    giBase<<<384, 256, 0, stream>>>(Wih, content, style, bih, Mbuf, giB);
    for (int s = 0; s < 16; ++s)
        stepK<<<512, 256, 0, stream>>>(Mbuf, Whh, bhh, giB, hAll, hBf, s);
    projK<<<FLAT / 256, 256, 0, stream>>>(Wproj, bproj, hBf, out);
}